// Round 2
// baseline (415.395 us; speedup 1.0000x reference)
//
#include <hip/hip_runtime.h>

typedef __attribute__((ext_vector_type(4))) float f32x4;
typedef __attribute__((ext_vector_type(8))) short s16x8;
typedef __attribute__((ext_vector_type(4))) unsigned short u16x4;
typedef __attribute__((ext_vector_type(8))) unsigned short u16x8;

#define DEVINL __device__ __forceinline__

constexpr int Bb = 2;
constexpr int Ss = 2048;
constexpr int Hh = 2048;
constexpr int NH = 16;
constexpr int HD = 128;
constexpr int RD = 32;
constexpr float ATT_SCALE = 0.08838834764831845f; // 128^-0.5

DEVINL unsigned short f2bf(float f) {
    unsigned u = __float_as_uint(f);
    u += 0x7FFFu + ((u >> 16) & 1u);
    return (unsigned short)(u >> 16);
}
DEVINL float bf2f(unsigned short h) { return __uint_as_float(((unsigned)h) << 16); }

// ---------------- mask zero-scan ----------------
__global__ void zero_flag_k(int* f) { if (threadIdx.x == 0) *f = 0; }

__global__ void scan_mask_k(const float* __restrict__ m, int* __restrict__ flag) {
    size_t i = ((size_t)blockIdx.x * 256 + threadIdx.x) * 4;
    f32x4 v = *(const f32x4*)(m + i);
    int any = (v[0] != 0.f) || (v[1] != 0.f) || (v[2] != 0.f) || (v[3] != 0.f);
    if (__any(any)) { if ((threadIdx.x & 63) == 0) atomicOr(flag, 1); }
}

// ---------------- fp32 -> bf16 convert (hidden) ----------------
__global__ void convH_k(const float* __restrict__ x, unsigned short* __restrict__ y) {
    size_t i = (size_t)blockIdx.x * 256 + threadIdx.x;
    f32x4 a = *(const f32x4*)(x + i * 8);
    f32x4 b = *(const f32x4*)(x + i * 8 + 4);
    u16x8 o;
    o[0] = f2bf(a[0]); o[1] = f2bf(a[1]); o[2] = f2bf(a[2]); o[3] = f2bf(a[3]);
    o[4] = f2bf(b[0]); o[5] = f2bf(b[1]); o[6] = f2bf(b[2]); o[7] = f2bf(b[3]);
    *(u16x8*)(y + i * 8) = o;
}

// ---------------- fp32 -> bf16 transpose (weights: W[R][C] -> Wt[C][R]) ----------------
__global__ void convT_k(const float* __restrict__ W, unsigned short* __restrict__ Wt,
                        int R, int C) {
    __shared__ float tile[32][33];
    int c0 = blockIdx.x * 32, r0 = blockIdx.y * 32;
    int t = threadIdx.x;
    int rr = t >> 3, cc = (t & 7) * 4;
    f32x4 v = *(const f32x4*)(W + (size_t)(r0 + rr) * C + c0 + cc);
    tile[rr][cc + 0] = v[0]; tile[rr][cc + 1] = v[1];
    tile[rr][cc + 2] = v[2]; tile[rr][cc + 3] = v[3];
    __syncthreads();
    u16x4 o;
    o[0] = f2bf(tile[cc + 0][rr]); o[1] = f2bf(tile[cc + 1][rr]);
    o[2] = f2bf(tile[cc + 2][rr]); o[3] = f2bf(tile[cc + 3][rr]);
    *(u16x4*)(Wt + (size_t)(c0 + rr) * R + r0 + cc) = o;
}

// ---------------- GEMM: C[M][N] = A[M][K](bf16) * Bt[N][K](bf16)^T ----------------
// 128x128 tile, BK=64, 4 waves (2x2), each wave 64x64 out (4x4 frags of 16x16x32)
template<int OUTF32>
__global__ __launch_bounds__(256)
void gemm_bt_k(const unsigned short* __restrict__ A, const unsigned short* __restrict__ Bt,
               float* __restrict__ Cf, unsigned short* __restrict__ Cb,
               int M, int N, int K) {
    __shared__ char lds[128 * 64 * 2 * 2]; // As 16KB + Bs 16KB
    char* As = lds;
    char* Bs = lds + 128 * 64 * 2;
    int t = threadIdx.x, w = t >> 6, ln = t & 63, lr = ln & 15, lg = ln >> 4;
    int m0 = blockIdx.y * 128, n0 = blockIdx.x * 128;
    int wr = w >> 1, wc = w & 1;

    f32x4 acc[4][4];
#pragma unroll
    for (int i = 0; i < 4; ++i)
#pragma unroll
        for (int j = 0; j < 4; ++j) { acc[i][j][0] = 0.f; acc[i][j][1] = 0.f; acc[i][j][2] = 0.f; acc[i][j][3] = 0.f; }

    for (int k0 = 0; k0 < K; k0 += 64) {
        __syncthreads();
        // stage A,Bt tiles: 1024 16B chunks each; row = 128B (64 bf16), XOR-swizzled
#pragma unroll
        for (int vv = 0; vv < 4; ++vv) {
            int ci = vv * 256 + t;
            int row = ci >> 3, sb = (ci & 7) << 4;
            u16x8 da = *(const u16x8*)(A + (size_t)(m0 + row) * K + k0 + (sb >> 1));
            *(u16x8*)(As + row * 128 + (sb ^ ((row & 7) << 4))) = da;
            u16x8 db = *(const u16x8*)(Bt + (size_t)(n0 + row) * K + k0 + (sb >> 1));
            *(u16x8*)(Bs + row * 128 + (sb ^ ((row & 7) << 4))) = db;
        }
        __syncthreads();
#pragma unroll
        for (int kc = 0; kc < 2; ++kc) {
            s16x8 af[4], bfr[4];
#pragma unroll
            for (int i = 0; i < 4; ++i) {
                int rowa = wr * 64 + i * 16 + lr;
                af[i] = *(const s16x8*)(As + rowa * 128 + ((kc * 64 + lg * 16) ^ ((rowa & 7) << 4)));
                int rowb = wc * 64 + i * 16 + lr;
                bfr[i] = *(const s16x8*)(Bs + rowb * 128 + ((kc * 64 + lg * 16) ^ ((rowb & 7) << 4)));
            }
#pragma unroll
            for (int i = 0; i < 4; ++i)
#pragma unroll
                for (int j = 0; j < 4; ++j)
                    acc[i][j] = __builtin_amdgcn_mfma_f32_16x16x32_bf16(af[i], bfr[j], acc[i][j], 0, 0, 0);
        }
    }
    // epilogue: C/D layout col=l&15, row=(l>>4)*4+r
#pragma unroll
    for (int i = 0; i < 4; ++i)
#pragma unroll
        for (int j = 0; j < 4; ++j)
#pragma unroll
            for (int r = 0; r < 4; ++r) {
                int gr = m0 + wr * 64 + i * 16 + lg * 4 + r;
                int gc = n0 + wc * 64 + j * 16 + lr;
                float vv = acc[i][j][r];
                if (OUTF32) Cf[(size_t)gr * N + gc] = vv;
                else        Cb[(size_t)gr * N + gc] = f2bf(vv);
            }
}

// ---------------- RoPE in-place on q,k rotary dims of qkv ----------------
__global__ void rope_qk_k(unsigned short* __restrict__ qkv) {
    int bs = blockIdx.x;          // b*S + s
    int s = bs & (Ss - 1);
    int t = threadIdx.x;
    int h = t >> 4, d0 = (t & 15) * 8;
    if (d0 >= RD) return;         // only d0 in {0,8,16,24}
    size_t row = (size_t)bs * 6144;
#pragma unroll
    for (int qk = 0; qk < 2; ++qk) {
        size_t base = row + qk * 2048 + h * 128;
        u16x8 o = *(const u16x8*)(qkv + base + d0);
        u16x8 p = *(const u16x8*)(qkv + base + (d0 ^ 16));
        u16x8 res;
#pragma unroll
        for (int e = 0; e < 8; ++e) {
            int d = d0 + e; int fi = d & 15;
            float invf = __expf(fi * -0.5756462732485114f); // 10000^(-fi/16)
            float ang = (float)s * invf;
            float sn, cs;
            sincosf(ang, &sn, &cs);
            float xo = bf2f(o[e]), xp = bf2f(p[e]);
            float vv = (d < 16) ? (xo * cs - xp * sn) : (xo * cs + xp * sn);
            res[e] = f2bf(vv);
        }
        *(u16x8*)(qkv + base + d0) = res;
    }
}

// ---------------- V transpose: qkv v-part -> Vt[bh][d][s] ----------------
__global__ void vtrans_k(const unsigned short* __restrict__ qkv, unsigned short* __restrict__ Vt) {
    __shared__ unsigned short tile[64][40];
    int bh = blockIdx.x; int b = bh >> 4, h = bh & 15;
    int s0 = blockIdx.y * 64, d0 = blockIdx.z * 32;
    int t = threadIdx.x;
    int r = t >> 2, c8 = (t & 3) * 8;
    u16x8 v = *(const u16x8*)(qkv + ((size_t)(b * Ss + s0 + r)) * 6144 + 4096 + h * 128 + d0 + c8);
#pragma unroll
    for (int e = 0; e < 8; ++e) tile[r][c8 + e] = v[e];
    __syncthreads();
    int dr = t >> 3, sc = (t & 7) * 8;
    u16x8 o;
#pragma unroll
    for (int e = 0; e < 8; ++e) o[e] = tile[sc + e][dr];
    *(u16x8*)(Vt + ((size_t)bh * HD + d0 + dr) * Ss + s0 + sc) = o;
}

// ---------------- flash attention ----------------
// grid (bh=32, qtile=32), 256 thr, 4 waves x 16 q-rows, KB=64
__global__ __launch_bounds__(256)
void attn_k(const unsigned short* __restrict__ qkv, const unsigned short* __restrict__ Vt,
            const float* __restrict__ mask, unsigned short* __restrict__ ctxb,
            const int* __restrict__ flag) {
    __shared__ char ldsK[64 * 256];        // [64 kk][128 d] bf16, swizzled
    __shared__ char ldsV[128 * 128];       // [128 d][64 kk] bf16, swizzled
    __shared__ unsigned short ldsP[4][16 * 72]; // per-wave P, padded stride 72
    int bh = blockIdx.x; int b = bh >> 4, h = bh & 15;
    int qt = blockIdx.y;
    int t = threadIdx.x, w = t >> 6, ln = t & 63, lr = ln & 15, lg = ln >> 4;
    int useMask = *flag;
    int qrow0 = qt * 64 + w * 16;

    s16x8 qf[4];
    size_t qbase = ((size_t)(b * Ss + qrow0 + lr)) * 6144 + h * 128;
#pragma unroll
    for (int kc = 0; kc < 4; ++kc) qf[kc] = *(const s16x8*)(qkv + qbase + kc * 32 + lg * 8);

    float mr[4], lsum[4];
    f32x4 ctxa[8];
#pragma unroll
    for (int r = 0; r < 4; ++r) { mr[r] = -1e30f; lsum[r] = 0.f; }
#pragma unroll
    for (int dn = 0; dn < 8; ++dn) { ctxa[dn][0] = 0.f; ctxa[dn][1] = 0.f; ctxa[dn][2] = 0.f; ctxa[dn][3] = 0.f; }
    const float* mrow = mask + (size_t)b * Ss * Ss;

    for (int kk0 = 0; kk0 < Ss; kk0 += 64) {
        __syncthreads();
#pragma unroll
        for (int vv = 0; vv < 4; ++vv) {
            int ci = vv * 256 + t;
            int row = ci >> 4, sb = (ci & 15) << 4;   // K tile: 256B rows
            u16x8 dk = *(const u16x8*)(qkv + ((size_t)(b * Ss + kk0 + row)) * 6144 + 2048 + h * 128 + (sb >> 1));
            *(u16x8*)(ldsK + row * 256 + (sb ^ ((row & 7) << 4))) = dk;
            int vrow = ci >> 3, vsb = (ci & 7) << 4;  // V tile: 128B rows
            u16x8 dv = *(const u16x8*)(Vt + ((size_t)bh * HD + vrow) * Ss + kk0 + (vsb >> 1));
            *(u16x8*)(ldsV + vrow * 128 + (vsb ^ ((vrow & 7) << 4))) = dv;
        }
        __syncthreads();

        // QK^T: S[q][kk], 4 n-tiles
        f32x4 sfr[4];
#pragma unroll
        for (int n = 0; n < 4; ++n) {
            f32x4 sacc = {0.f, 0.f, 0.f, 0.f};
            int krow = n * 16 + lr;
            const char* kb = ldsK + krow * 256;
            int sw = (krow & 7) << 4;
#pragma unroll
            for (int kc = 0; kc < 4; ++kc) {
                s16x8 kf = *(const s16x8*)(kb + ((kc * 64 + lg * 16) ^ sw));
                sacc = __builtin_amdgcn_mfma_f32_16x16x32_bf16(qf[kc], kf, sacc, 0, 0, 0);
            }
            sfr[n] = sacc;
        }
        // scale + optional mask
#pragma unroll
        for (int n = 0; n < 4; ++n)
#pragma unroll
            for (int r = 0; r < 4; ++r) {
                float vv = sfr[n][r] * ATT_SCALE;
                if (useMask)
                    vv += mrow[(size_t)(qrow0 + lg * 4 + r) * Ss + kk0 + n * 16 + lr];
                sfr[n][r] = vv;
            }
        // online softmax
        float al[4];
#pragma unroll
        for (int r = 0; r < 4; ++r) {
            float rm = fmaxf(fmaxf(sfr[0][r], sfr[1][r]), fmaxf(sfr[2][r], sfr[3][r]));
            rm = fmaxf(rm, __shfl_xor(rm, 1));
            rm = fmaxf(rm, __shfl_xor(rm, 2));
            rm = fmaxf(rm, __shfl_xor(rm, 4));
            rm = fmaxf(rm, __shfl_xor(rm, 8));
            float mn = fmaxf(mr[r], rm);
            al[r] = __expf(mr[r] - mn);
            mr[r] = mn;
            lsum[r] *= al[r];
        }
#pragma unroll
        for (int dn = 0; dn < 8; ++dn)
#pragma unroll
            for (int r = 0; r < 4; ++r) ctxa[dn][r] *= al[r];
        float rs[4] = {0.f, 0.f, 0.f, 0.f};
#pragma unroll
        for (int n = 0; n < 4; ++n)
#pragma unroll
            for (int r = 0; r < 4; ++r) {
                float p = __expf(sfr[n][r] - mr[r]);
                sfr[n][r] = p; rs[r] += p;
            }
#pragma unroll
        for (int r = 0; r < 4; ++r) {
            rs[r] += __shfl_xor(rs[r], 1);
            rs[r] += __shfl_xor(rs[r], 2);
            rs[r] += __shfl_xor(rs[r], 4);
            rs[r] += __shfl_xor(rs[r], 8);
            lsum[r] += rs[r];
        }
        // P -> LDS (re-fragment for PV A-operand)
        unsigned short* pw = ldsP[w];
#pragma unroll
        for (int n = 0; n < 4; ++n)
#pragma unroll
            for (int r = 0; r < 4; ++r)
                pw[(lg * 4 + r) * 72 + n * 16 + lr] = f2bf(sfr[n][r]);
        asm volatile("s_waitcnt lgkmcnt(0)" ::: "memory");
        s16x8 pa[2];
#pragma unroll
        for (int c2 = 0; c2 < 2; ++c2)
            pa[c2] = *(const s16x8*)((const char*)pw + lr * 144 + c2 * 64 + lg * 16);
        // PV: ctx[q][d] += P[q][kk] * Vt[d][kk]^T
#pragma unroll
        for (int dn = 0; dn < 8; ++dn) {
            int vr = dn * 16 + lr;
            const char* vb = ldsV + vr * 128;
            int swv = (vr & 7) << 4;
#pragma unroll
            for (int c2 = 0; c2 < 2; ++c2) {
                s16x8 vf = *(const s16x8*)(vb + ((c2 * 64 + lg * 16) ^ swv));
                ctxa[dn] = __builtin_amdgcn_mfma_f32_16x16x32_bf16(pa[c2], vf, ctxa[dn], 0, 0, 0);
            }
        }
    }
    // epilogue: divide by lsum, write ctx (B,S,H) bf16
#pragma unroll
    for (int r = 0; r < 4; ++r) {
        float inv = 1.f / lsum[r];
#pragma unroll
        for (int dn = 0; dn < 8; ++dn)
            ctxb[((size_t)(b * Ss + qrow0 + lg * 4 + r)) * Hh + h * 128 + dn * 16 + lr] =
                f2bf(ctxa[dn][r] * inv);
    }
}

extern "C" void kernel_launch(void* const* d_in, const int* in_sizes, int n_in,
                              void* d_out, int out_size, void* d_ws, size_t ws_size,
                              hipStream_t stream) {
    (void)in_sizes; (void)n_in; (void)out_size; (void)ws_size;
    const float* hidden = (const float*)d_in[0];
    const float* mask   = (const float*)d_in[1];
    const float* Wqkv   = (const float*)d_in[2];
    const float* Wout   = (const float*)d_in[3];
    float* out = (float*)d_out;

    char* ws = (char*)d_ws;
    size_t off = 0;
    auto alloc = [&](size_t bytes) { char* p = ws + off; off += (bytes + 255) & ~(size_t)255; return p; };
    unsigned short* hbf   = (unsigned short*)alloc((size_t)8388608 * 2);   // hidden bf16; later aliased as ctx
    unsigned short* wqkvT = (unsigned short*)alloc((size_t)12582912 * 2);  // (6144,2048)
    unsigned short* woutT = (unsigned short*)alloc((size_t)4194304 * 2);   // (2048,2048)
    unsigned short* qkv   = (unsigned short*)alloc((size_t)25165824 * 2);  // (4096,6144)
    unsigned short* Vt    = (unsigned short*)alloc((size_t)8388608 * 2);   // (32,128,2048)
    int* flag             = (int*)alloc(256);
    unsigned short* ctx = hbf; // alias: hidden bf16 dead after QKV GEMM

    zero_flag_k<<<1, 64, 0, stream>>>(flag);
    scan_mask_k<<<2048, 256, 0, stream>>>(mask, flag);
    convH_k<<<4096, 256, 0, stream>>>(hidden, hbf);
    convT_k<<<dim3(192, 64), 256, 0, stream>>>(Wqkv, wqkvT, 2048, 6144);
    convT_k<<<dim3(64, 64), 256, 0, stream>>>(Wout, woutT, 2048, 2048);
    gemm_bt_k<0><<<dim3(48, 32), 256, 0, stream>>>(hbf, wqkvT, nullptr, qkv, 4096, 6144, 2048);
    rope_qk_k<<<4096, 256, 0, stream>>>(qkv);
    vtrans_k<<<dim3(32, 32, 4), 256, 0, stream>>>(qkv, Vt);
    attn_k<<<dim3(32, 32), 256, 0, stream>>>(qkv, Vt, mask, ctx, flag);
    gemm_bt_k<1><<<dim3(16, 32), 256, 0, stream>>>(ctx, woutT, out, nullptr, 4096, 2048, 2048);
}

// Round 3
// 314.774 us; speedup vs baseline: 1.3197x; 1.3197x over previous
//
#include <hip/hip_runtime.h>

typedef __attribute__((ext_vector_type(4))) float f32x4;
typedef __attribute__((ext_vector_type(8))) short s16x8;
typedef __attribute__((ext_vector_type(4))) unsigned short u16x4;
typedef __attribute__((ext_vector_type(8))) unsigned short u16x8;

#define DEVINL __device__ __forceinline__

constexpr int Bb = 2;
constexpr int Ss = 2048;
constexpr int Hh = 2048;
constexpr int NH = 16;
constexpr int HD = 128;
constexpr float ATT_SCALE = 0.08838834764831845f;   // 128^-0.5
constexpr float CEXP = ATT_SCALE * 1.44269504089f;  // scale * log2(e)
constexpr float INV_SCALE = 11.313708498984761f;    // 1/scale
constexpr float RAW_THR = 90.50966799f;             // 8/scale (defer-max threshold)

DEVINL unsigned short f2bf(float f) {
    unsigned u = __float_as_uint(f);
    u += 0x7FFFu + ((u >> 16) & 1u);
    return (unsigned short)(u >> 16);
}
DEVINL float bf2f(unsigned short h) { return __uint_as_float(((unsigned)h) << 16); }
DEVINL float fexp2(float x) { return __builtin_amdgcn_exp2f(x); }

// global -> LDS direct (16B per lane). Dest must be linear in lane order.
DEVINL void gl16(const void* g, void* l) {
    __builtin_amdgcn_global_load_lds((const __attribute__((address_space(1))) void*)g,
                                     (__attribute__((address_space(3))) void*)l, 16, 0, 0);
}

// ---------------- mask zero-scan ----------------
__global__ void zero_flag_k(int* f) { if (threadIdx.x == 0) *f = 0; }

__global__ void scan_mask_k(const float* __restrict__ m, int* __restrict__ flag) {
    size_t i = ((size_t)blockIdx.x * 256 + threadIdx.x) * 4;
    f32x4 v = *(const f32x4*)(m + i);
    int any = (v[0] != 0.f) || (v[1] != 0.f) || (v[2] != 0.f) || (v[3] != 0.f);
    if (__any(any)) { if ((threadIdx.x & 63) == 0) atomicOr(flag, 1); }
}

// ---------------- fp32 -> bf16 convert (hidden) ----------------
__global__ void convH_k(const float* __restrict__ x, unsigned short* __restrict__ y) {
    size_t i = (size_t)blockIdx.x * 256 + threadIdx.x;
    f32x4 a = *(const f32x4*)(x + i * 8);
    f32x4 b = *(const f32x4*)(x + i * 8 + 4);
    u16x8 o;
    o[0] = f2bf(a[0]); o[1] = f2bf(a[1]); o[2] = f2bf(a[2]); o[3] = f2bf(a[3]);
    o[4] = f2bf(b[0]); o[5] = f2bf(b[1]); o[6] = f2bf(b[2]); o[7] = f2bf(b[3]);
    *(u16x8*)(y + i * 8) = o;
}

// ---------------- fp32 -> bf16 transpose (weights: W[R][C] -> Wt[C][R]) ----------------
__global__ void convT_k(const float* __restrict__ W, unsigned short* __restrict__ Wt,
                        int R, int C) {
    __shared__ float tile[32][33];
    int c0 = blockIdx.x * 32, r0 = blockIdx.y * 32;
    int t = threadIdx.x;
    int rr = t >> 3, cc = (t & 7) * 4;
    f32x4 v = *(const f32x4*)(W + (size_t)(r0 + rr) * C + c0 + cc);
    tile[rr][cc + 0] = v[0]; tile[rr][cc + 1] = v[1];
    tile[rr][cc + 2] = v[2]; tile[rr][cc + 3] = v[3];
    __syncthreads();
    u16x4 o;
    o[0] = f2bf(tile[cc + 0][rr]); o[1] = f2bf(tile[cc + 1][rr]);
    o[2] = f2bf(tile[cc + 2][rr]); o[3] = f2bf(tile[cc + 3][rr]);
    *(u16x4*)(Wt + (size_t)(c0 + rr) * R + r0 + cc) = o;
}

// ---------------- GEMM: C[M][N] = A[M][K](bf16) * Bt[N][K](bf16)^T ----------------
// 128x128 tile, BK=64, 4 waves (2x2). MODE 0: bf16 out + fused RoPE on cols<4096.
// MODE 1: f32 out. Staging via global_load_lds (linear dest, inverse-swizzled src).
template<int MODE>
__global__ __launch_bounds__(256)
void gemm_bt_k(const unsigned short* __restrict__ A, const unsigned short* __restrict__ Bt,
               float* __restrict__ Cf, unsigned short* __restrict__ Cb,
               int M, int N, int K) {
    __shared__ char lds[128 * 64 * 2 * 2]; // As 16KB + Bs 16KB
    char* As = lds;
    char* Bs = lds + 128 * 64 * 2;
    int t = threadIdx.x, w = t >> 6, ln = t & 63, lr = ln & 15, lg = ln >> 4;
    // bijective XCD swizzle (grid %8==0): each XCD gets a contiguous chunk
    int f = blockIdx.x;
    int cpx = gridDim.x >> 3;
    int s = (f & 7) * cpx + (f >> 3);
    int nbn = N >> 7;
    int nb = s % nbn, mb = s / nbn;
    int m0 = mb * 128, n0 = nb * 128;
    int wr = w >> 1, wc = w & 1;
    const char* Abt = (const char*)A;
    const char* Bbt = (const char*)Bt;

    f32x4 acc[4][4];
#pragma unroll
    for (int i = 0; i < 4; ++i)
#pragma unroll
        for (int j = 0; j < 4; ++j) { acc[i][j][0] = 0.f; acc[i][j][1] = 0.f; acc[i][j][2] = 0.f; acc[i][j][3] = 0.f; }

    for (int k0 = 0; k0 < K; k0 += 64) {
        __syncthreads();
        // stage: 1024 16B chunks each; LDS row = 128B; dest linear, src col pre-swizzled
#pragma unroll
        for (int vv = 0; vv < 4; ++vv) {
            int ci = vv * 256 + t;
            int row = ci >> 3, cb = (ci & 7) << 4;
            int sc = cb ^ ((row & 7) << 4);
            gl16(Abt + ((size_t)(m0 + row) * K + k0) * 2 + sc, As + ci * 16);
            gl16(Bbt + ((size_t)(n0 + row) * K + k0) * 2 + sc, Bs + ci * 16);
        }
        __syncthreads();
#pragma unroll
        for (int kc = 0; kc < 2; ++kc) {
            s16x8 af[4], bfr[4];
#pragma unroll
            for (int i = 0; i < 4; ++i) {
                int rowa = wr * 64 + i * 16 + lr;
                af[i] = *(const s16x8*)(As + rowa * 128 + ((kc * 64 + lg * 16) ^ ((rowa & 7) << 4)));
                int rowb = wc * 64 + i * 16 + lr;
                bfr[i] = *(const s16x8*)(Bs + rowb * 128 + ((kc * 64 + lg * 16) ^ ((rowb & 7) << 4)));
            }
#pragma unroll
            for (int i = 0; i < 4; ++i)
#pragma unroll
                for (int j = 0; j < 4; ++j)
                    acc[i][j] = __builtin_amdgcn_mfma_f32_16x16x32_bf16(af[i], bfr[j], acc[i][j], 0, 0, 0);
        }
    }

    // fused RoPE (QKV gemm only): cols with (gc&127)<32 and gc<4096 (q,k sections).
    // For wc==0 waves: j=0 holds d=lr (0..15), j=1 holds d=16+lr -> rotate pair in-lane.
    if (MODE == 0 && n0 < 4096 && wc == 0) {
        float invf = fexp2((float)lr * -0.83048202372f); // 10000^(-lr/16)
#pragma unroll
        for (int i = 0; i < 4; ++i)
#pragma unroll
            for (int r = 0; r < 4; ++r) {
                int srow = (m0 + wr * 64 + i * 16 + lg * 4 + r) & (Ss - 1);
                float sn, cs;
                sincosf((float)srow * invf, &sn, &cs);
                float x1 = acc[i][0][r], x2 = acc[i][1][r];
                acc[i][0][r] = x1 * cs - x2 * sn;
                acc[i][1][r] = x2 * cs + x1 * sn;
            }
    }

    // epilogue: C/D layout col=l&15, row=(l>>4)*4+r
#pragma unroll
    for (int i = 0; i < 4; ++i)
#pragma unroll
        for (int j = 0; j < 4; ++j)
#pragma unroll
            for (int r = 0; r < 4; ++r) {
                int gr = m0 + wr * 64 + i * 16 + lg * 4 + r;
                int gc = n0 + wc * 64 + j * 16 + lr;
                float vv = acc[i][j][r];
                if (MODE == 1) Cf[(size_t)gr * N + gc] = vv;
                else           Cb[(size_t)gr * N + gc] = f2bf(vv);
            }
}

// ---------------- V transpose: qkv v-part -> Vt[bh][d][s] ----------------
__global__ void vtrans_k(const unsigned short* __restrict__ qkv, unsigned short* __restrict__ Vt) {
    __shared__ unsigned short tile[64][40];
    int bh = blockIdx.x; int b = bh >> 4, h = bh & 15;
    int s0 = blockIdx.y * 64, d0 = blockIdx.z * 32;
    int t = threadIdx.x;
    int r = t >> 2, c8 = (t & 3) * 8;
    u16x8 v = *(const u16x8*)(qkv + ((size_t)(b * Ss + s0 + r)) * 6144 + 4096 + h * 128 + d0 + c8);
#pragma unroll
    for (int e = 0; e < 8; ++e) tile[r][c8 + e] = v[e];
    __syncthreads();
    int dr = t >> 3, sc = (t & 7) * 8;
    u16x8 o;
#pragma unroll
    for (int e = 0; e < 8; ++e) o[e] = tile[sc + e][dr];
    *(u16x8*)(Vt + ((size_t)bh * HD + d0 + dr) * Ss + s0 + sc) = o;
}

// ---------------- flash attention ----------------
// 512 blocks (32 bh x 16 qt), 512 thr = 8 waves x 16 q-rows, KVBLK=64.
// Swapped QK^T: S^T = mfma(K, Q) -> lane owns q = lane&15; in-register softmax.
__global__ __launch_bounds__(512)
void attn_k(const unsigned short* __restrict__ qkv, const unsigned short* __restrict__ Vt,
            const float* __restrict__ mask, unsigned short* __restrict__ ctxb,
            const int* __restrict__ flag) {
    __shared__ char ldsK[64 * 256];            // [64 kk][128 d] bf16, swizzled
    __shared__ char ldsV[128 * 128];           // [128 d][64 kk] bf16, swizzled
    __shared__ unsigned short ldsP[8][1024];   // per-wave P [16 q][64 kk], swizzled
    int f = blockIdx.x;
    int swzb = (f & 7) * 64 + (f >> 3);        // XCD swizzle: 16 qt of 4 bh per XCD chunk
    int bh = swzb >> 4, qt = swzb & 15;
    int b = bh >> 4, h = bh & 15;
    int t = threadIdx.x, w = t >> 6, ln = t & 63, lr = ln & 15, lg = ln >> 4;
    int useMask = *flag;
    int qw0 = qt * 128 + w * 16;
    const char* qkvB = (const char*)qkv;
    const char* VtB = (const char*)Vt;

    // Q fragments (B-operand): lane holds Q[q=qw0+lr][d = kc*32 + lg*8 + e]
    s16x8 qf[4];
    size_t qbase = ((size_t)(b * Ss + qw0 + lr)) * 6144 + h * 128;
#pragma unroll
    for (int kc = 0; kc < 4; ++kc) qf[kc] = *(const s16x8*)(qkv + qbase + kc * 32 + lg * 8);

    float mr = -3e38f, lsum = 0.f;  // per-lane, q-row = lane&15, raw score units
    f32x4 ctxa[8];
#pragma unroll
    for (int dn = 0; dn < 8; ++dn) { ctxa[dn][0] = 0.f; ctxa[dn][1] = 0.f; ctxa[dn][2] = 0.f; ctxa[dn][3] = 0.f; }
    const float* mrow = mask + (size_t)b * Ss * Ss;

    for (int kk0 = 0; kk0 < Ss; kk0 += 64) {
        __syncthreads();
        // stage K (1024 chunks, 256B rows) + V (1024 chunks, 128B rows) via global_load_lds
#pragma unroll
        for (int c = 0; c < 2; ++c) {
            int ci = c * 512 + t;
            int krow = ci >> 4, kcb = (ci & 15) << 4;
            gl16(qkvB + (((size_t)(b * Ss + kk0 + krow)) * 6144 + 2048 + h * 128) * 2 + (kcb ^ ((krow & 7) << 4)),
                 ldsK + ci * 16);
            int vrow = ci >> 3, vcb = (ci & 7) << 4;
            gl16(VtB + (((size_t)(bh * 128 + vrow)) * 2048 + kk0) * 2 + (vcb ^ ((vrow & 7) << 4)),
                 ldsV + ci * 16);
        }
        __syncthreads();

        // S^T[kk][q] = K·Q^T : per n, lane holds kk = n*16 + lg*4 + r, q = lr
        f32x4 st[4];
#pragma unroll
        for (int n = 0; n < 4; ++n) {
            f32x4 sacc = {0.f, 0.f, 0.f, 0.f};
            const char* kb = ldsK + (n * 16 + lr) * 256;
            int sw = (lr & 7) << 4;
#pragma unroll
            for (int kc = 0; kc < 4; ++kc) {
                s16x8 kf = *(const s16x8*)(kb + ((kc * 64 + lg * 16) ^ sw));
                sacc = __builtin_amdgcn_mfma_f32_16x16x32_bf16(kf, qf[kc], sacc, 0, 0, 0);
            }
            st[n] = sacc;
        }
        if (useMask) {
#pragma unroll
            for (int n = 0; n < 4; ++n)
#pragma unroll
                for (int r = 0; r < 4; ++r)
                    st[n][r] += mrow[(size_t)(qw0 + lr) * Ss + kk0 + n * 16 + lg * 4 + r] * INV_SCALE;
        }
        // row max for q = lr (in-lane 16 values + reduce over lg via xor 16,32)
        float pmax = st[0][0];
#pragma unroll
        for (int n = 0; n < 4; ++n)
#pragma unroll
            for (int r = 0; r < 4; ++r) pmax = fmaxf(pmax, st[n][r]);
        pmax = fmaxf(pmax, __shfl_xor(pmax, 16));
        pmax = fmaxf(pmax, __shfl_xor(pmax, 32));
        // defer-max: rescale only if max grew by > 8/scale (raw units)
        bool need = pmax > mr + RAW_THR;
        if (__any(need)) {
            float mn = fmaxf(mr, pmax);
            float al = fexp2((mr - mn) * CEXP);
            mr = mn;
            lsum *= al;
            float a0 = __shfl(al, lg * 4 + 0), a1 = __shfl(al, lg * 4 + 1);
            float a2 = __shfl(al, lg * 4 + 2), a3 = __shfl(al, lg * 4 + 3);
#pragma unroll
            for (int dn = 0; dn < 8; ++dn) {
                ctxa[dn][0] *= a0; ctxa[dn][1] *= a1; ctxa[dn][2] *= a2; ctxa[dn][3] *= a3;
            }
        }
        float mC = mr * CEXP;
        float rs = 0.f;
        u16x4 pk[4];
#pragma unroll
        for (int n = 0; n < 4; ++n)
#pragma unroll
            for (int r = 0; r < 4; ++r) {
                float p = fexp2(st[n][r] * CEXP - mC);
                rs += p;
                pk[n][r] = f2bf(p);
            }
        rs += __shfl_xor(rs, 16);
        rs += __shfl_xor(rs, 32);
        lsum += rs;
        // P -> per-wave LDS [q=lr][kk], packed b64 writes, XOR-swizzled rows
        char* pw = (char*)ldsP[w];
        int swp = (lr & 7) << 4;
#pragma unroll
        for (int n = 0; n < 4; ++n)
            *(u16x4*)(pw + lr * 128 + ((32 * n + 8 * lg) ^ swp)) = pk[n];
        asm volatile("s_waitcnt lgkmcnt(0)" ::: "memory");
        s16x8 pa[2];
#pragma unroll
        for (int c2 = 0; c2 < 2; ++c2)
            pa[c2] = *(const s16x8*)(pw + lr * 128 + ((64 * c2 + 16 * lg) ^ swp));
        // PV: ctx[q][d] += P[q][kk] * V[kk][d]
#pragma unroll
        for (int dn = 0; dn < 8; ++dn) {
            const char* vb = ldsV + (dn * 16 + lr) * 128;
#pragma unroll
            for (int c2 = 0; c2 < 2; ++c2) {
                s16x8 vf = *(const s16x8*)(vb + ((c2 * 64 + lg * 16) ^ swp));
                ctxa[dn] = __builtin_amdgcn_mfma_f32_16x16x32_bf16(pa[c2], vf, ctxa[dn], 0, 0, 0);
            }
        }
    }
    // epilogue: divide by lsum (fetch per-row via shfl), write ctx bf16
    float l0 = 1.f / __shfl(lsum, lg * 4 + 0), l1 = 1.f / __shfl(lsum, lg * 4 + 1);
    float l2 = 1.f / __shfl(lsum, lg * 4 + 2), l3 = 1.f / __shfl(lsum, lg * 4 + 3);
#pragma unroll
    for (int dn = 0; dn < 8; ++dn) {
        size_t base = ((size_t)(b * Ss + qw0)) * Hh + h * 128 + dn * 16 + lr;
        ctxb[base + (size_t)(lg * 4 + 0) * Hh] = f2bf(ctxa[dn][0] * l0);
        ctxb[base + (size_t)(lg * 4 + 1) * Hh] = f2bf(ctxa[dn][1] * l1);
        ctxb[base + (size_t)(lg * 4 + 2) * Hh] = f2bf(ctxa[dn][2] * l2);
        ctxb[base + (size_t)(lg * 4 + 3) * Hh] = f2bf(ctxa[dn][3] * l3);
    }
}

extern "C" void kernel_launch(void* const* d_in, const int* in_sizes, int n_in,
                              void* d_out, int out_size, void* d_ws, size_t ws_size,
                              hipStream_t stream) {
    (void)in_sizes; (void)n_in; (void)out_size; (void)ws_size;
    const float* hidden = (const float*)d_in[0];
    const float* mask   = (const float*)d_in[1];
    const float* Wqkv   = (const float*)d_in[2];
    const float* Wout   = (const float*)d_in[3];
    float* out = (float*)d_out;

    char* ws = (char*)d_ws;
    size_t off = 0;
    auto alloc = [&](size_t bytes) { char* p = ws + off; off += (bytes + 255) & ~(size_t)255; return p; };
    unsigned short* hbf   = (unsigned short*)alloc((size_t)8388608 * 2);   // hidden bf16; later aliased as ctx
    unsigned short* wqkvT = (unsigned short*)alloc((size_t)12582912 * 2);  // (6144,2048)
    unsigned short* woutT = (unsigned short*)alloc((size_t)4194304 * 2);   // (2048,2048)
    unsigned short* qkv   = (unsigned short*)alloc((size_t)25165824 * 2);  // (4096,6144)
    unsigned short* Vt    = (unsigned short*)alloc((size_t)8388608 * 2);   // (32,128,2048)
    int* flag             = (int*)alloc(256);
    unsigned short* ctx = hbf; // alias: hidden bf16 dead after QKV GEMM

    zero_flag_k<<<1, 64, 0, stream>>>(flag);
    scan_mask_k<<<2048, 256, 0, stream>>>(mask, flag);
    convH_k<<<4096, 256, 0, stream>>>(hidden, hbf);
    convT_k<<<dim3(192, 64), 256, 0, stream>>>(Wqkv, wqkvT, 2048, 6144);
    convT_k<<<dim3(64, 64), 256, 0, stream>>>(Wout, woutT, 2048, 2048);
    gemm_bt_k<0><<<1536, 256, 0, stream>>>(hbf, wqkvT, nullptr, qkv, 4096, 6144, 2048);
    vtrans_k<<<dim3(32, 32, 4), 256, 0, stream>>>(qkv, Vt);
    attn_k<<<512, 512, 0, stream>>>(qkv, Vt, mask, ctx, flag);
    gemm_bt_k<1><<<512, 256, 0, stream>>>(ctx, woutT, out, nullptr, 4096, 2048, 2048);
}